// Round 2
// baseline (4919.794 us; speedup 1.0000x reference)
//
#include <hip/hip_runtime.h>
#include <hip/hip_bf16.h>

#define B_   16
#define CIN_ 32
#define S_   512
#define D_   256
#define H_   8
#define L_   4
#define FF_  1024
#define HD_  32
#define EPS_ 1e-5f

__device__ __forceinline__ float gelu_f(float v) {
    return 0.5f * v * (1.0f + erff(v * 0.70710678118654752f));
}

// ---------------- conv1 + bn + gelu: x (B,CIN,S) f32 -> out (B,D,S) f32 -----
__global__ void conv1_kernel(const float* __restrict__ x, const float* __restrict__ w,
                             const float* __restrict__ cb, const float* __restrict__ g,
                             const float* __restrict__ bb, float* __restrict__ out) {
    int b = blockIdx.x >> 8;
    int o = blockIdx.x & 255;
    __shared__ float ws[CIN_ * 7];
    for (int i = threadIdx.x; i < CIN_ * 7; i += 256) ws[i] = w[o * CIN_ * 7 + i];
    __syncthreads();
    float cbias = cb[o];
    float scale = g[o] * rsqrtf(1.0f + EPS_);
    float shift = bb[o];
    for (int s = threadIdx.x; s < S_; s += 256) {
        float acc = cbias;
        for (int i = 0; i < CIN_; ++i) {
            const float* xr = x + (b * CIN_ + i) * S_;
            const float* wr = ws + i * 7;
#pragma unroll
            for (int kk = 0; kk < 7; ++kk) {
                int sp = s + kk - 3;
                if (sp >= 0 && sp < S_) acc += xr[sp] * wr[kk];
            }
        }
        out[(b * D_ + o) * S_ + s] = gelu_f(acc * scale + shift);
    }
}

// ---------------- conv2 + bn + gelu: h (B,D,S) f32 -> out (B,D,S) f32 -------
__global__ void conv2_kernel(const float* __restrict__ h, const float* __restrict__ w,
                             const float* __restrict__ cb, const float* __restrict__ g,
                             const float* __restrict__ bb, float* __restrict__ out) {
    int b = blockIdx.x >> 8;
    int o = blockIdx.x & 255;
    __shared__ float ws[D_ * 5];
    for (int i = threadIdx.x; i < D_ * 5; i += 256) ws[i] = w[o * D_ * 5 + i];
    __syncthreads();
    float cbias = cb[o];
    float scale = g[o] * rsqrtf(1.0f + EPS_);
    float shift = bb[o];
    for (int s = threadIdx.x; s < S_; s += 256) {
        float acc = cbias;
        for (int i = 0; i < D_; ++i) {
            const float* hr = h + (b * D_ + i) * S_;
            const float* wr = ws + i * 5;
#pragma unroll
            for (int kk = 0; kk < 5; ++kk) {
                int sp = s + kk - 2;
                if (sp >= 0 && sp < S_) acc += hr[sp] * wr[kk];
            }
        }
        out[(b * D_ + o) * S_ + s] = gelu_f(acc * scale + shift);
    }
}

// ---------------- transpose + positional encoding: (B,D,S) -> t (B,S,D) -----
__global__ void pe_kernel(const float* __restrict__ h, float* __restrict__ t) {
    int idx = blockIdx.x * 256 + threadIdx.x;
    if (idx >= B_ * S_ * D_) return;
    int d = idx & (D_ - 1);
    int s = (idx >> 8) & (S_ - 1);
    int b = idx >> 17;
    int m2 = d & ~1;  // 2m
    float div = expf((float)m2 * (-9.210340371976184f / 256.0f));
    float ang = (float)s * div * 0.5f;  // scale = D/S = 0.5
    float pe = (d & 1) ? cosf(ang) : sinf(ang);
    t[idx] = h[(b * D_ + d) * S_ + s] + pe;
}

// ---------------- layernorm over last dim (D=256), one block per row --------
__global__ void ln_kernel(const float* __restrict__ x, const float* __restrict__ g,
                          const float* __restrict__ bt, float* __restrict__ out) {
    int row = blockIdx.x;
    int tid = threadIdx.x;  // 256 == D
    float v = x[row * D_ + tid];
    float s1 = v, s2 = v * v;
    __shared__ float red[8];
#pragma unroll
    for (int off = 32; off; off >>= 1) {
        s1 += __shfl_xor(s1, off);
        s2 += __shfl_xor(s2, off);
    }
    int wave = tid >> 6;
    if ((tid & 63) == 0) { red[wave] = s1; red[4 + wave] = s2; }
    __syncthreads();
    if (tid == 0) {
        float a = red[0] + red[1] + red[2] + red[3];
        float q = red[4] + red[5] + red[6] + red[7];
        float mu = a * (1.0f / D_);
        float var = q * (1.0f / D_) - mu * mu;
        red[0] = mu;
        red[1] = rsqrtf(var + EPS_);
    }
    __syncthreads();
    float mu = red[0], inv = red[1];
    out[row * D_ + tid] = (v - mu) * inv * g[tid] + bt[tid];
}

// ---------------- tiled fp32 GEMM: out[M,N] = A[M,K] @ W[K,N] (+bias,+gelu,+res)
template <bool BIAS, bool RES, bool GELU_ACT>
__global__ void gemm_kernel(const float* __restrict__ A, const float* __restrict__ W,
                            const float* __restrict__ bias, const float* __restrict__ res,
                            float* __restrict__ out, int M, int N, int K) {
    __shared__ float As[16][65];  // [k][m], padded
    __shared__ float Ws[16][65];  // [k][n], padded
    int n0 = blockIdx.x * 64;
    int m0 = blockIdx.y * 64;
    int tid = threadIdx.x;
    int tx = tid & 15, ty = tid >> 4;
    float c[4][4] = {};
    for (int k0 = 0; k0 < K; k0 += 16) {
#pragma unroll
        for (int r = 0; r < 4; ++r) {
            int idx = tid + r * 256;
            int kka = idx & 15, mm = idx >> 4;
            As[kka][mm] = A[(m0 + mm) * K + k0 + kka];
            int kkw = idx >> 6, nn = idx & 63;
            Ws[kkw][nn] = W[(k0 + kkw) * N + n0 + nn];
        }
        __syncthreads();
#pragma unroll
        for (int kk = 0; kk < 16; ++kk) {
            float a[4], w[4];
#pragma unroll
            for (int i = 0; i < 4; ++i) a[i] = As[kk][ty * 4 + i];
#pragma unroll
            for (int j = 0; j < 4; ++j) w[j] = Ws[kk][tx * 4 + j];
#pragma unroll
            for (int i = 0; i < 4; ++i)
#pragma unroll
                for (int j = 0; j < 4; ++j) c[i][j] += a[i] * w[j];
        }
        __syncthreads();
    }
#pragma unroll
    for (int i = 0; i < 4; ++i) {
        int m = m0 + ty * 4 + i;
#pragma unroll
        for (int j = 0; j < 4; ++j) {
            int n = n0 + tx * 4 + j;
            float v = c[i][j];
            if (BIAS) v += bias[n];
            if (GELU_ACT) v = gelu_f(v);
            if (RES) v += res[m * N + n];
            out[m * N + n] = v;
        }
    }
}

// ---------------- attention: one block per (b,h,i) row ----------------------
__global__ void attn_kernel(const float* __restrict__ q, const float* __restrict__ k,
                            const float* __restrict__ v, const float* __restrict__ bias_l,
                            float* __restrict__ ctx) {
    int blk = blockIdx.x;
    int i = blk & (S_ - 1);
    int bh = blk >> 9;
    int h = bh & (H_ - 1);
    int b = bh >> 3;
    __shared__ float p[S_];
    __shared__ float qs[HD_];
    __shared__ float red2[8];
    __shared__ float cred[8][32];
    int tid = threadIdx.x;
    if (tid < HD_) qs[tid] = q[(b * S_ + i) * D_ + h * HD_ + tid];
    __syncthreads();
    const float scale = 0.17677669529663687f;  // 32^-0.5
    float lmax = -1e30f;
    for (int j = tid; j < S_; j += 256) {
        const float* kr = k + (b * S_ + j) * D_ + h * HD_;
        float acc = 0.0f;
#pragma unroll
        for (int d = 0; d < HD_; ++d) acc += qs[d] * kr[d];
        acc = acc * scale + bias_l[(i - j + S_ - 1) * H_ + h];
        p[j] = acc;
        lmax = fmaxf(lmax, acc);
    }
#pragma unroll
    for (int off = 32; off; off >>= 1) lmax = fmaxf(lmax, __shfl_xor(lmax, off));
    int wave = tid >> 6;
    if ((tid & 63) == 0) red2[wave] = lmax;
    __syncthreads();
    if (tid == 0) red2[0] = fmaxf(fmaxf(red2[0], red2[1]), fmaxf(red2[2], red2[3]));
    __syncthreads();
    float mx = red2[0];
    float lsum = 0.0f;
    for (int j = tid; j < S_; j += 256) {
        float e = expf(p[j] - mx);
        p[j] = e;
        lsum += e;
    }
#pragma unroll
    for (int off = 32; off; off >>= 1) lsum += __shfl_xor(lsum, off);
    if ((tid & 63) == 0) red2[4 + wave] = lsum;
    __syncthreads();
    float inv = 1.0f / (red2[4] + red2[5] + red2[6] + red2[7]);
    int d = tid & 31, chunk = tid >> 5;
    float acc = 0.0f;
    int j0 = chunk * 64;
    for (int j = j0; j < j0 + 64; ++j) acc += p[j] * v[(b * S_ + j) * D_ + h * HD_ + d];
    cred[chunk][d] = acc;
    __syncthreads();
    if (tid < 32) {
        float s = 0.0f;
#pragma unroll
        for (int c2 = 0; c2 < 8; ++c2) s += cred[c2][tid];
        ctx[(b * S_ + i) * D_ + h * HD_ + tid] = s * inv;
    }
}

extern "C" void kernel_launch(void* const* d_in, const int* in_sizes, int n_in,
                              void* d_out, int out_size, void* d_ws, size_t ws_size,
                              hipStream_t stream) {
    const float* x        = (const float*)d_in[0];
    const float* conv1_w  = (const float*)d_in[1];
    const float* conv1_b  = (const float*)d_in[2];
    const float* bn1_g    = (const float*)d_in[3];
    const float* bn1_b    = (const float*)d_in[4];
    const float* conv2_w  = (const float*)d_in[5];
    const float* conv2_b  = (const float*)d_in[6];
    const float* bn2_g    = (const float*)d_in[7];
    const float* bn2_b    = (const float*)d_in[8];
    const float* ln1_g    = (const float*)d_in[9];
    const float* ln1_b    = (const float*)d_in[10];
    const float* wq       = (const float*)d_in[11];
    const float* wk       = (const float*)d_in[12];
    const float* wv       = (const float*)d_in[13];
    const float* wo       = (const float*)d_in[14];
    const float* bo       = (const float*)d_in[15];
    const float* bias_tab = (const float*)d_in[16];
    const float* ln2_g    = (const float*)d_in[17];
    const float* ln2_b    = (const float*)d_in[18];
    const float* w1       = (const float*)d_in[19];
    const float* b1       = (const float*)d_in[20];
    const float* w2       = (const float*)d_in[21];
    const float* b2       = (const float*)d_in[22];
    const float* fn_g     = (const float*)d_in[23];
    const float* fn_b     = (const float*)d_in[24];

    const int BSD = B_ * S_ * D_;      // 2,097,152
    float* ws   = (float*)d_ws;
    float* t    = ws;                  // BSD
    float* xn   = t + BSD;             // BSD
    float* qb   = xn + BSD;            // BSD  (also conv h1, ff1 part)
    float* kb   = qb + BSD;            // BSD  (also conv h2)
    float* vb   = kb + BSD;            // BSD
    float* ctx  = vb + BSD;            // BSD
    float* ff1  = qb;                  // B*S*FF = 4*BSD, aliases qb..ctx (dead then)
    (void)ws_size; (void)in_sizes; (void)n_in; (void)out_size;

    const int M = B_ * S_;  // 8192

    // tokenizer
    conv1_kernel<<<B_ * D_, 256, 0, stream>>>(x, conv1_w, conv1_b, bn1_g, bn1_b, qb);
    conv2_kernel<<<B_ * D_, 256, 0, stream>>>(qb, conv2_w, conv2_b, bn2_g, bn2_b, kb);
    pe_kernel<<<(BSD + 255) / 256, 256, 0, stream>>>(kb, t);

    for (int l = 0; l < L_; ++l) {
        ln_kernel<<<M, 256, 0, stream>>>(t, ln1_g + l * D_, ln1_b + l * D_, xn);
        gemm_kernel<false, false, false><<<dim3(D_ / 64, M / 64), 256, 0, stream>>>(
            xn, wq + l * D_ * D_, nullptr, nullptr, qb, M, D_, D_);
        gemm_kernel<false, false, false><<<dim3(D_ / 64, M / 64), 256, 0, stream>>>(
            xn, wk + l * D_ * D_, nullptr, nullptr, kb, M, D_, D_);
        gemm_kernel<false, false, false><<<dim3(D_ / 64, M / 64), 256, 0, stream>>>(
            xn, wv + l * D_ * D_, nullptr, nullptr, vb, M, D_, D_);
        attn_kernel<<<B_ * H_ * S_, 256, 0, stream>>>(
            qb, kb, vb, bias_tab + l * (2 * S_ - 1) * H_, ctx);
        gemm_kernel<true, true, false><<<dim3(D_ / 64, M / 64), 256, 0, stream>>>(
            ctx, wo + l * D_ * D_, bo + l * D_, t, t, M, D_, D_);
        ln_kernel<<<M, 256, 0, stream>>>(t, ln2_g + l * D_, ln2_b + l * D_, xn);
        gemm_kernel<true, false, true><<<dim3(FF_ / 64, M / 64), 256, 0, stream>>>(
            xn, w1 + l * D_ * FF_, b1 + l * FF_, nullptr, ff1, M, FF_, D_);
        gemm_kernel<true, true, false><<<dim3(D_ / 64, M / 64), 256, 0, stream>>>(
            ff1, w2 + l * FF_ * D_, b2 + l * D_, t, t, M, D_, FF_);
    }
    ln_kernel<<<M, 256, 0, stream>>>(t, fn_g, fn_b, (float*)d_out);
}

// Round 3
// 2166.807 us; speedup vs baseline: 2.2705x; 2.2705x over previous
//
#include <hip/hip_runtime.h>
#include <hip/hip_bf16.h>
#include <stdint.h>

#define B_   16
#define CIN_ 32
#define S_   512
#define D_   256
#define H_   8
#define L_   4
#define FF_  1024
#define HD_  32
#define EPS_ 1e-5f

typedef __hip_bfloat16 bf16;
typedef __attribute__((ext_vector_type(8))) short short8;
typedef __attribute__((ext_vector_type(4))) float floatx4;

__device__ __forceinline__ float b2f(bf16 v) { return __bfloat162float(v); }
__device__ __forceinline__ bf16 f2b(float v) { return __float2bfloat16(v); }
__device__ __forceinline__ float gelu_f(float v) {
    return 0.5f * v * (1.0f + erff(v * 0.70710678118654752f));
}
__device__ __forceinline__ float pe_val(int s, int d) {
    int m2 = d & ~1;
    float div = expf((float)m2 * (-9.210340371976184f / 256.0f));
    float ang = (float)s * div * 0.5f;  // scale = D/S = 0.5
    return (d & 1) ? cosf(ang) : sinf(ang);
}
__device__ __forceinline__ void unp(uint32_t w, float& lo, float& hi) {
    lo = __uint_as_float(w << 16);
    hi = __uint_as_float(w & 0xffff0000u);
}

// ---------------- weight transpose-cast: dst[n][k] = src[k][n] --------------
// src (L,K,N) f32, dst rows at (rowoff+n), row stride K, per-layer dst stride lds_
__global__ void wtrans_kernel(const float* __restrict__ src, bf16* __restrict__ dst,
                              int K, int N, long lss, long lds_, int rowoff) {
    __shared__ float tile[32][33];
    int l = blockIdx.z;
    int n0 = blockIdx.x * 32, k0 = blockIdx.y * 32;
    int tx = threadIdx.x & 31, ty0 = threadIdx.x >> 5;
#pragma unroll
    for (int r = 0; r < 4; ++r) {
        int ky = r * 8 + ty0;
        tile[ky][tx] = src[l * lss + (long)(k0 + ky) * N + n0 + tx];
    }
    __syncthreads();
#pragma unroll
    for (int r = 0; r < 4; ++r) {
        int ny = r * 8 + ty0;
        dst[l * lds_ + (long)(rowoff + n0 + ny) * K + k0 + tx] = f2b(tile[tx][ny]);
    }
}

// ---------------- conv weight prep (fold BN scale) + shift vectors ----------
// blocks 0..15: conv1 (w (256,32,7) -> c1w[o][kk*32+i]), 16..31: conv2
__global__ void convprep_kernel(const float* __restrict__ w1c, const float* __restrict__ cb1,
                                const float* __restrict__ g1, const float* __restrict__ bb1,
                                const float* __restrict__ w2c, const float* __restrict__ cb2,
                                const float* __restrict__ g2, const float* __restrict__ bb2,
                                bf16* __restrict__ c1w, bf16* __restrict__ c2w,
                                float* __restrict__ sh1, float* __restrict__ sh2) {
    int bid = blockIdx.x;
    int ty = threadIdx.x >> 4, t16 = threadIdx.x & 15;
    float rinv = rsqrtf(1.0f + EPS_);
    if (bid < 16) {
        int o = bid * 16 + ty;
        float scale = g1[o] * rinv;
        if (t16 == 0) sh1[o] = cb1[o] * scale + bb1[o];
        for (int j = t16; j < CIN_ * 7; j += 16) {
            int i = j / 7, kk = j % 7;
            c1w[o * 224 + kk * 32 + i] = f2b(w1c[o * 224 + i * 7 + kk] * scale);
        }
    } else {
        int o = (bid - 16) * 16 + ty;
        float scale = g2[o] * rinv;
        if (t16 == 0) sh2[o] = cb2[o] * scale + bb2[o];
        for (int j = t16; j < D_ * 5; j += 16) {
            int i = j / 5, kk = j % 5;
            c2w[o * 1280 + kk * 256 + i] = f2b(w2c[o * 1280 + i * 5 + kk] * scale);
        }
    }
}

// ---------------- im2col for conv1: x (B,CIN,S) f32 -> col (B*S, 224) bf16 --
__global__ void im2col1_kernel(const float* __restrict__ x, bf16* __restrict__ col) {
    int kk = blockIdx.x, b = blockIdx.y;
    for (int t = threadIdx.x; t < 512 * 32; t += 256) {
        int s = t & 511, i = t >> 9;
        int sp = s + kk - 3;
        float v = (sp >= 0 && sp < 512) ? x[((b << 5) + i) * 512 + sp] : 0.0f;
        col[(long)((b << 9) + s) * 224 + kk * 32 + i] = f2b(v);
    }
}

// ---------------- im2col for conv2: h1 (B*S, 256) bf16 -> col (B*S, 1280) ---
__global__ void im2col2_kernel(const bf16* __restrict__ h1, bf16* __restrict__ col) {
    int kk = blockIdx.x, b = blockIdx.y;
    for (int t = threadIdx.x; t < 512 * 32; t += 256) {
        int c = t & 31, s = t >> 5;
        int sp = s + kk - 2;
        uint4 v = {0u, 0u, 0u, 0u};
        if (sp >= 0 && sp < 512)
            v = *(const uint4*)((const char*)h1 + ((long)((b << 9) + sp) * 256 + c * 8) * 2);
        *(uint4*)((char*)col + ((long)((b << 9) + s) * 1280 + kk * 256 + c * 8) * 2) = v;
    }
}

// ---------------- layernorm (D=256): t f32 -> bf16 or f32 -------------------
template <bool OUT_BF16>
__global__ void ln_kernel(const float* __restrict__ x, const float* __restrict__ g,
                          const float* __restrict__ bt, float* __restrict__ out_f,
                          bf16* __restrict__ out_b) {
    int row = blockIdx.x;
    int tid = threadIdx.x;  // 256 == D
    float v = x[(long)row * D_ + tid];
    float s1 = v, s2 = v * v;
    __shared__ float red[8];
#pragma unroll
    for (int off = 32; off; off >>= 1) {
        s1 += __shfl_xor(s1, off);
        s2 += __shfl_xor(s2, off);
    }
    int wave = tid >> 6;
    if ((tid & 63) == 0) { red[wave] = s1; red[4 + wave] = s2; }
    __syncthreads();
    if (tid == 0) {
        float a = red[0] + red[1] + red[2] + red[3];
        float q = red[4] + red[5] + red[6] + red[7];
        float mu = a * (1.0f / D_);
        float var = q * (1.0f / D_) - mu * mu;
        red[0] = mu;
        red[1] = rsqrtf(var + EPS_);
    }
    __syncthreads();
    float y = (v - red[0]) * red[1] * g[tid] + bt[tid];
    if (OUT_BF16) out_b[(long)row * D_ + tid] = f2b(y);
    else          out_f[(long)row * D_ + tid] = y;
}

// ---------------- async global->LDS staging (width 16) ----------------------
template <int ROWS>
__device__ __forceinline__ void stage_tile(const char* gbase, int row_stride_b, int k_byte_off,
                                           char* lds_base, int tid) {
    constexpr int ROUNDS = ROWS * 64 / 4096;
    char* lp = lds_base + (tid & 192) * 16;  // wave-uniform: wave*1024
#pragma unroll
    for (int r = 0; r < ROUNDS; ++r) {
        int off = r * 4096 + tid * 16;
        int row = off >> 6, col = off & 63;
        const char* gp = gbase + (long)row * row_stride_b + k_byte_off + col;
        __builtin_amdgcn_global_load_lds((const __attribute__((address_space(1))) void*)gp,
                                         (__attribute__((address_space(3))) void*)(lp + r * 4096),
                                         16, 0, 0);
    }
}

// ---------------- bf16 MFMA GEMM: out = A(M,K) @ Wt(N,K)^T ------------------
enum { FB = 1, FG = 2, FR = 4, FO16 = 8, FPE = 16 };

template <int BM, int BN, int WM, int WN, int FLAGS>
__global__ void gemm_bf16(const bf16* __restrict__ A, const bf16* __restrict__ Wt,
                          const float* __restrict__ bias, const float* __restrict__ res,
                          float* __restrict__ outf, bf16* __restrict__ outb,
                          int M, int N, int K) {
    constexpr int WAVES_M = BM / WM;
    constexpr int FM = WM / 16, FN = WN / 16;
    __shared__ short As[BM * 32];
    __shared__ short Bs[BN * 32];
    int tid = threadIdx.x;
    int wave = tid >> 6, lane = tid & 63;
    int m0 = blockIdx.y * BM, n0 = blockIdx.x * BN;
    int wm = (wave % WAVES_M) * WM, wn = (wave / WAVES_M) * WN;
    int frow = lane & 15, fquad = lane >> 4;
    floatx4 acc[FM][FN] = {};
    const char* Ab = (const char*)A + (long)m0 * K * 2;
    const char* Bb = (const char*)Wt + (long)n0 * K * 2;
    for (int kb = 0; kb < K * 2; kb += 64) {
        stage_tile<BM>(Ab, K * 2, kb, (char*)As, tid);
        stage_tile<BN>(Bb, K * 2, kb, (char*)Bs, tid);
        __syncthreads();
        short8 af[FM], bfr[FN];
#pragma unroll
        for (int i = 0; i < FM; ++i)
            af[i] = *(const short8*)(As + (wm + i * 16 + frow) * 32 + fquad * 8);
#pragma unroll
        for (int j = 0; j < FN; ++j)
            bfr[j] = *(const short8*)(Bs + (wn + j * 16 + frow) * 32 + fquad * 8);
#pragma unroll
        for (int i = 0; i < FM; ++i)
#pragma unroll
            for (int j = 0; j < FN; ++j)
                acc[i][j] = __builtin_amdgcn_mfma_f32_16x16x32_bf16(af[i], bfr[j], acc[i][j], 0, 0, 0);
        __syncthreads();
    }
#pragma unroll
    for (int i = 0; i < FM; ++i) {
#pragma unroll
        for (int j = 0; j < FN; ++j) {
#pragma unroll
            for (int r = 0; r < 4; ++r) {
                int row = m0 + wm + i * 16 + fquad * 4 + r;
                int col = n0 + wn + j * 16 + frow;
                float v = acc[i][j][r];
                if (FLAGS & FB) v += bias[col];
                if (FLAGS & FG) v = gelu_f(v);
                if (FLAGS & FPE) v += pe_val(row & 511, col);
                if (FLAGS & FR) v += res[(long)row * N + col];
                if (FLAGS & FO16) outb[(long)row * N + col] = f2b(v);
                else              outf[(long)row * N + col] = v;
            }
        }
    }
}

// ---------------- attention: one block per (b,h,i); qkv (M,768) bf16 --------
__global__ void attn_kernel(const bf16* __restrict__ qkv, const float* __restrict__ bias_l,
                            bf16* __restrict__ ctx) {
    int blk = blockIdx.x;
    int i = blk & (S_ - 1);
    int bh = blk >> 9;
    int h = bh & (H_ - 1);
    int b = bh >> 3;
    __shared__ float p[S_];
    __shared__ float qs[HD_];
    __shared__ float red2[8];
    __shared__ float Vl[64][33];
    __shared__ float cred[8][32];
    int tid = threadIdx.x;
    long base = (long)(b * S_) * 768;
    if (tid < HD_) qs[tid] = b2f(qkv[base + (long)i * 768 + h * 32 + tid]);
    __syncthreads();
    const float scale = 0.17677669529663687f;  // 32^-0.5
    float lmax = -1e30f;
    for (int j = tid; j < S_; j += 256) {
        const uint4* kr = (const uint4*)(qkv + base + (long)j * 768 + 256 + h * 32);
        float acc = 0.0f;
#pragma unroll
        for (int q4 = 0; q4 < 4; ++q4) {
            uint4 u = kr[q4];
            float a0, a1, a2, a3, a4, a5, a6, a7;
            unp(u.x, a0, a1); unp(u.y, a2, a3); unp(u.z, a4, a5); unp(u.w, a6, a7);
            int e = q4 * 8;
            acc += qs[e] * a0 + qs[e + 1] * a1 + qs[e + 2] * a2 + qs[e + 3] * a3
                 + qs[e + 4] * a4 + qs[e + 5] * a5 + qs[e + 6] * a6 + qs[e + 7] * a7;
        }
        acc = acc * scale + bias_l[(i - j + S_ - 1) * H_ + h];
        p[j] = acc;
        lmax = fmaxf(lmax, acc);
    }
#pragma unroll
    for (int off = 32; off; off >>= 1) lmax = fmaxf(lmax, __shfl_xor(lmax, off));
    int wave = tid >> 6;
    if ((tid & 63) == 0) red2[wave] = lmax;
    __syncthreads();
    if (tid == 0) red2[0] = fmaxf(fmaxf(red2[0], red2[1]), fmaxf(red2[2], red2[3]));
    __syncthreads();
    float mx = red2[0];
    float lsum = 0.0f;
    for (int j = tid; j < S_; j += 256) {
        float e = expf(p[j] - mx);
        p[j] = e;
        lsum += e;
    }
#pragma unroll
    for (int off = 32; off; off >>= 1) lsum += __shfl_xor(lsum, off);
    if ((tid & 63) == 0) red2[4 + wave] = lsum;
    __syncthreads();
    float inv = 1.0f / (red2[4] + red2[5] + red2[6] + red2[7]);
    int d = tid & 31, grp = tid >> 5;
    float acc = 0.0f;
    int vr = tid >> 2, vq = tid & 3;
    for (int j0 = 0; j0 < S_; j0 += 64) {
        uint4 u = *(const uint4*)(qkv + base + (long)(j0 + vr) * 768 + 512 + h * 32 + vq * 8);
        float a0, a1, a2, a3, a4, a5, a6, a7;
        unp(u.x, a0, a1); unp(u.y, a2, a3); unp(u.z, a4, a5); unp(u.w, a6, a7);
        int e = vq * 8;
        Vl[vr][e] = a0; Vl[vr][e + 1] = a1; Vl[vr][e + 2] = a2; Vl[vr][e + 3] = a3;
        Vl[vr][e + 4] = a4; Vl[vr][e + 5] = a5; Vl[vr][e + 6] = a6; Vl[vr][e + 7] = a7;
        __syncthreads();
#pragma unroll
        for (int jj = 0; jj < 8; ++jj) {
            int j = grp * 8 + jj;
            acc += p[j0 + j] * Vl[j][d];
        }
        __syncthreads();
    }
    cred[grp][d] = acc;
    __syncthreads();
    if (tid < 32) {
        float s = 0.0f;
#pragma unroll
        for (int c2 = 0; c2 < 8; ++c2) s += cred[c2][tid];
        ctx[(base / 3) + (long)i * 256 + h * 32 + tid] = f2b(s * inv);
    }
}

extern "C" void kernel_launch(void* const* d_in, const int* in_sizes, int n_in,
                              void* d_out, int out_size, void* d_ws, size_t ws_size,
                              hipStream_t stream) {
    const float* x        = (const float*)d_in[0];
    const float* conv1_w  = (const float*)d_in[1];
    const float* conv1_b  = (const float*)d_in[2];
    const float* bn1_g    = (const float*)d_in[3];
    const float* bn1_b    = (const float*)d_in[4];
    const float* conv2_w  = (const float*)d_in[5];
    const float* conv2_b  = (const float*)d_in[6];
    const float* bn2_g    = (const float*)d_in[7];
    const float* bn2_b    = (const float*)d_in[8];
    const float* ln1_g    = (const float*)d_in[9];
    const float* ln1_b    = (const float*)d_in[10];
    const float* wq       = (const float*)d_in[11];
    const float* wk       = (const float*)d_in[12];
    const float* wv       = (const float*)d_in[13];
    const float* wo       = (const float*)d_in[14];
    const float* bo       = (const float*)d_in[15];
    const float* bias_tab = (const float*)d_in[16];
    const float* ln2_g    = (const float*)d_in[17];
    const float* ln2_b    = (const float*)d_in[18];
    const float* w1       = (const float*)d_in[19];
    const float* b1       = (const float*)d_in[20];
    const float* w2       = (const float*)d_in[21];
    const float* b2       = (const float*)d_in[22];
    const float* fn_g     = (const float*)d_in[23];
    const float* fn_b     = (const float*)d_in[24];
    (void)in_sizes; (void)n_in; (void)out_size; (void)ws_size;

    const int M = B_ * S_;  // 8192
    char* wsb = (char*)d_ws;
    float* t    = (float*)wsb;                          // [0, 8M)
    bf16* qkv   = (bf16*)(wsb + (8u << 20));            // [8M, 20M)
    bf16* h1    = (bf16*)(wsb + (8u << 20));            // alias (4 MB, dead before qkv)
    char* reg2  = wsb + (20u << 20);                    // [20M, 40M)
    bf16* ff1   = (bf16*)reg2;                          // 16 MB
    bf16* xnctx = (bf16*)(reg2 + (16u << 20));          // 4 MB (xn and ctx, disjoint lifetimes)
    bf16* col1  = (bf16*)reg2;                          // alias (3.5 MB)
    bf16* col2  = (bf16*)reg2;                          // alias (20 MB)
    bf16* wqkvT = (bf16*)(wsb + (40u << 20));           // L*768*256
    bf16* woT   = wqkvT + (long)L_ * 768 * 256;         // L*256*256
    bf16* w1T   = woT + (long)L_ * 256 * 256;           // L*1024*256
    bf16* w2T   = w1T + (long)L_ * 1024 * 256;          // L*256*1024
    bf16* c1w   = w2T + (long)L_ * 256 * 1024;          // 256*224
    bf16* c2w   = c1w + 256 * 224;                      // 256*1280
    float* sh1  = (float*)(c2w + 256 * 1280);           // 256
    float* sh2  = sh1 + 256;                            // 256

    // ---- weight prep ----
    wtrans_kernel<<<dim3(8, 8, L_), 256, 0, stream>>>(wq, wqkvT, 256, 256, 65536, 768 * 256, 0);
    wtrans_kernel<<<dim3(8, 8, L_), 256, 0, stream>>>(wk, wqkvT, 256, 256, 65536, 768 * 256, 256);
    wtrans_kernel<<<dim3(8, 8, L_), 256, 0, stream>>>(wv, wqkvT, 256, 256, 65536, 768 * 256, 512);
    wtrans_kernel<<<dim3(8, 8, L_), 256, 0, stream>>>(wo, woT, 256, 256, 65536, 65536, 0);
    wtrans_kernel<<<dim3(32, 8, L_), 256, 0, stream>>>(w1, w1T, 256, 1024, 262144, 262144, 0);
    wtrans_kernel<<<dim3(8, 32, L_), 256, 0, stream>>>(w2, w2T, 1024, 256, 262144, 262144, 0);
    convprep_kernel<<<32, 256, 0, stream>>>(conv1_w, conv1_b, bn1_g, bn1_b,
                                            conv2_w, conv2_b, bn2_g, bn2_b,
                                            c1w, c2w, sh1, sh2);

    // ---- tokenizer: conv1 -> h1 (bf16, B*S x 256), conv2 -> t (f32, +PE) ----
    im2col1_kernel<<<dim3(7, B_), 256, 0, stream>>>(x, col1);
    gemm_bf16<128, 64, 32, 64, FB | FG | FO16><<<dim3(4, 64), 256, 0, stream>>>(
        col1, c1w, sh1, nullptr, nullptr, h1, M, 256, 224);
    im2col2_kernel<<<dim3(5, B_), 256, 0, stream>>>(h1, col2);
    gemm_bf16<128, 64, 32, 64, FB | FG | FPE><<<dim3(4, 64), 256, 0, stream>>>(
        col2, c2w, sh2, nullptr, t, nullptr, M, 256, 1280);

    // ---- transformer layers ----
    for (int l = 0; l < L_; ++l) {
        ln_kernel<true><<<M, 256, 0, stream>>>(t, ln1_g + l * D_, ln1_b + l * D_, nullptr, xnctx);
        gemm_bf16<128, 128, 64, 64, FO16><<<dim3(6, 64), 256, 0, stream>>>(
            xnctx, wqkvT + (long)l * 768 * 256, nullptr, nullptr, nullptr, qkv, M, 768, 256);
        attn_kernel<<<B_ * H_ * S_, 256, 0, stream>>>(
            qkv, bias_tab + (long)l * (2 * S_ - 1) * H_, xnctx);
        gemm_bf16<128, 64, 32, 64, FB | FR><<<dim3(4, 64), 256, 0, stream>>>(
            xnctx, woT + (long)l * 65536, bo + l * D_, t, t, nullptr, M, 256, 256);
        ln_kernel<true><<<M, 256, 0, stream>>>(t, ln2_g + l * D_, ln2_b + l * D_, nullptr, xnctx);
        gemm_bf16<128, 128, 64, 64, FB | FG | FO16><<<dim3(8, 64), 256, 0, stream>>>(
            xnctx, w1T + (long)l * 262144, b1 + l * FF_, nullptr, nullptr, ff1, M, 1024, 256);
        gemm_bf16<128, 64, 32, 64, FB | FR><<<dim3(4, 64), 256, 0, stream>>>(
            ff1, w2T + (long)l * 262144, b2 + l * D_, t, t, nullptr, M, 256, 1024);
    }
    ln_kernel<false><<<M, 256, 0, stream>>>(t, fn_g, fn_b, (float*)d_out, nullptr);
}

// Round 4
// 871.503 us; speedup vs baseline: 5.6452x; 2.4863x over previous
//
#include <hip/hip_runtime.h>
#include <hip/hip_bf16.h>
#include <stdint.h>

#define B_   16
#define CIN_ 32
#define S_   512
#define D_   256
#define H_   8
#define L_   4
#define FF_  1024
#define HD_  32
#define EPS_ 1e-5f

typedef __hip_bfloat16 bf16;
typedef __attribute__((ext_vector_type(8))) short short8;
typedef __attribute__((ext_vector_type(4))) float floatx4;

__device__ __forceinline__ float b2f(bf16 v) { return __bfloat162float(v); }
__device__ __forceinline__ bf16 f2b(float v) { return __float2bfloat16(v); }
__device__ __forceinline__ float gelu_f(float v) {
    return 0.5f * v * (1.0f + erff(v * 0.70710678118654752f));
}
__device__ __forceinline__ float pe_val(int s, int d) {
    int m2 = d & ~1;
    float div = expf((float)m2 * (-9.210340371976184f / 256.0f));
    float ang = (float)s * div * 0.5f;  // scale = D/S = 0.5
    return (d & 1) ? cosf(ang) : sinf(ang);
}

// ---------------- weight transpose-cast: dst[n][k] = src[k][n] --------------
__global__ void wtrans_kernel(const float* __restrict__ src, bf16* __restrict__ dst,
                              int K, int N, long lss, long lds_, int rowoff) {
    __shared__ float tile[32][33];
    int l = blockIdx.z;
    int n0 = blockIdx.x * 32, k0 = blockIdx.y * 32;
    int tx = threadIdx.x & 31, ty0 = threadIdx.x >> 5;
#pragma unroll
    for (int r = 0; r < 4; ++r) {
        int ky = r * 8 + ty0;
        tile[ky][tx] = src[l * lss + (long)(k0 + ky) * N + n0 + tx];
    }
    __syncthreads();
#pragma unroll
    for (int r = 0; r < 4; ++r) {
        int ny = r * 8 + ty0;
        dst[l * lds_ + (long)(rowoff + n0 + ny) * K + k0 + tx] = f2b(tile[tx][ny]);
    }
}

// ---------------- conv weight prep (fold BN scale) + shift vectors ----------
__global__ void convprep_kernel(const float* __restrict__ w1c, const float* __restrict__ cb1,
                                const float* __restrict__ g1, const float* __restrict__ bb1,
                                const float* __restrict__ w2c, const float* __restrict__ cb2,
                                const float* __restrict__ g2, const float* __restrict__ bb2,
                                bf16* __restrict__ c1w, bf16* __restrict__ c2w,
                                float* __restrict__ sh1, float* __restrict__ sh2) {
    int bid = blockIdx.x;
    int ty = threadIdx.x >> 4, t16 = threadIdx.x & 15;
    float rinv = rsqrtf(1.0f + EPS_);
    if (bid < 16) {
        int o = bid * 16 + ty;
        float scale = g1[o] * rinv;
        if (t16 == 0) sh1[o] = cb1[o] * scale + bb1[o];
        for (int j = t16; j < CIN_ * 7; j += 16) {
            int i = j / 7, kk = j % 7;
            c1w[o * 224 + kk * 32 + i] = f2b(w1c[o * 224 + i * 7 + kk] * scale);
        }
    } else {
        int o = (bid - 16) * 16 + ty;
        float scale = g2[o] * rinv;
        if (t16 == 0) sh2[o] = cb2[o] * scale + bb2[o];
        for (int j = t16; j < D_ * 5; j += 16) {
            int i = j / 5, kk = j % 5;
            c2w[o * 1280 + kk * 256 + i] = f2b(w2c[o * 1280 + i * 5 + kk] * scale);
        }
    }
}

// ---------------- im2col for conv1: x (B,CIN,S) f32 -> col (B*S, 224) bf16 --
__global__ void im2col1_kernel(const float* __restrict__ x, bf16* __restrict__ col) {
    int kk = blockIdx.x, b = blockIdx.y;
    for (int t = threadIdx.x; t < 512 * 32; t += 256) {
        int s = t & 511, i = t >> 9;
        int sp = s + kk - 3;
        float v = (sp >= 0 && sp < 512) ? x[((b << 5) + i) * 512 + sp] : 0.0f;
        col[(long)((b << 9) + s) * 224 + kk * 32 + i] = f2b(v);
    }
}

// ---------------- im2col for conv2: h1 (B*S, 256) bf16 -> col (B*S, 1280) ---
__global__ void im2col2_kernel(const bf16* __restrict__ h1, bf16* __restrict__ col) {
    int kk = blockIdx.x, b = blockIdx.y;
    for (int t = threadIdx.x; t < 512 * 32; t += 256) {
        int c = t & 31, s = t >> 5;
        int sp = s + kk - 2;
        uint4 v = {0u, 0u, 0u, 0u};
        if (sp >= 0 && sp < 512)
            v = *(const uint4*)((const char*)h1 + ((long)((b << 9) + sp) * 256 + c * 8) * 2);
        *(uint4*)((char*)col + ((long)((b << 9) + s) * 1280 + kk * 256 + c * 8) * 2) = v;
    }
}

// ---------------- layernorm (D=256): t f32 -> bf16 or f32 -------------------
template <bool OUT_BF16>
__global__ void ln_kernel(const float* __restrict__ x, const float* __restrict__ g,
                          const float* __restrict__ bt, float* __restrict__ out_f,
                          bf16* __restrict__ out_b) {
    int row = blockIdx.x;
    int tid = threadIdx.x;  // 256 == D
    float v = x[(long)row * D_ + tid];
    float s1 = v, s2 = v * v;
    __shared__ float red[8];
#pragma unroll
    for (int off = 32; off; off >>= 1) {
        s1 += __shfl_xor(s1, off);
        s2 += __shfl_xor(s2, off);
    }
    int wave = tid >> 6;
    if ((tid & 63) == 0) { red[wave] = s1; red[4 + wave] = s2; }
    __syncthreads();
    if (tid == 0) {
        float a = red[0] + red[1] + red[2] + red[3];
        float q = red[4] + red[5] + red[6] + red[7];
        float mu = a * (1.0f / D_);
        float var = q * (1.0f / D_) - mu * mu;
        red[0] = mu;
        red[1] = rsqrtf(var + EPS_);
    }
    __syncthreads();
    float y = (v - red[0]) * red[1] * g[tid] + bt[tid];
    if (OUT_BF16) out_b[(long)row * D_ + tid] = f2b(y);
    else          out_f[(long)row * D_ + tid] = y;
}

// ---------------- async global->LDS staging (width 16) ----------------------
template <int ROWS>
__device__ __forceinline__ void stage_tile(const char* gbase, int row_stride_b, int k_byte_off,
                                           char* lds_base, int tid) {
    constexpr int ROUNDS = ROWS * 64 / 4096;
    char* lp = lds_base + (tid & 192) * 16;  // wave-uniform: wave*1024
#pragma unroll
    for (int r = 0; r < ROUNDS; ++r) {
        int off = r * 4096 + tid * 16;
        int row = off >> 6, col = off & 63;
        const char* gp = gbase + (long)row * row_stride_b + k_byte_off + col;
        __builtin_amdgcn_global_load_lds((const __attribute__((address_space(1))) void*)gp,
                                         (__attribute__((address_space(3))) void*)(lp + r * 4096),
                                         16, 0, 0);
    }
}

// ---------------- bf16 MFMA GEMM: out = A(M,K) @ Wt(N,K)^T ------------------
enum { FB = 1, FG = 2, FR = 4, FO16 = 8, FPE = 16 };

template <int BM, int BN, int WM, int WN, int FLAGS>
__global__ void gemm_bf16(const bf16* __restrict__ A, const bf16* __restrict__ Wt,
                          const float* __restrict__ bias, const float* __restrict__ res,
                          float* __restrict__ outf, bf16* __restrict__ outb,
                          int M, int N, int K) {
    constexpr int WAVES_M = BM / WM;
    constexpr int FM = WM / 16, FN = WN / 16;
    __shared__ short As[BM * 32];
    __shared__ short Bs[BN * 32];
    int tid = threadIdx.x;
    int wave = tid >> 6, lane = tid & 63;
    int m0 = blockIdx.y * BM, n0 = blockIdx.x * BN;
    int wm = (wave % WAVES_M) * WM, wn = (wave / WAVES_M) * WN;
    int frow = lane & 15, fquad = lane >> 4;
    floatx4 acc[FM][FN] = {};
    const char* Ab = (const char*)A + (long)m0 * K * 2;
    const char* Bb = (const char*)Wt + (long)n0 * K * 2;
    for (int kb = 0; kb < K * 2; kb += 64) {
        stage_tile<BM>(Ab, K * 2, kb, (char*)As, tid);
        stage_tile<BN>(Bb, K * 2, kb, (char*)Bs, tid);
        __syncthreads();
        short8 af[FM], bfr[FN];
#pragma unroll
        for (int i = 0; i < FM; ++i)
            af[i] = *(const short8*)(As + (wm + i * 16 + frow) * 32 + fquad * 8);
#pragma unroll
        for (int j = 0; j < FN; ++j)
            bfr[j] = *(const short8*)(Bs + (wn + j * 16 + frow) * 32 + fquad * 8);
#pragma unroll
        for (int i = 0; i < FM; ++i)
#pragma unroll
            for (int j = 0; j < FN; ++j)
                acc[i][j] = __builtin_amdgcn_mfma_f32_16x16x32_bf16(af[i], bfr[j], acc[i][j], 0, 0, 0);
        __syncthreads();
    }
#pragma unroll
    for (int i = 0; i < FM; ++i) {
#pragma unroll
        for (int j = 0; j < FN; ++j) {
#pragma unroll
            for (int r = 0; r < 4; ++r) {
                int row = m0 + wm + i * 16 + fquad * 4 + r;
                int col = n0 + wn + j * 16 + frow;
                float v = acc[i][j][r];
                if (FLAGS & FB) v += bias[col];
                if (FLAGS & FG) v = gelu_f(v);
                if (FLAGS & FPE) v += pe_val(row & 511, col);
                if (FLAGS & FR) v += res[(long)row * N + col];
                if (FLAGS & FO16) outb[(long)row * N + col] = f2b(v);
                else              outf[(long)row * N + col] = v;
            }
        }
    }
}

// ---------------- V transpose: qkv (M,768) cols 512..767 -> Vt (B*H,32,512) -
__global__ void vtrans_kernel(const bf16* __restrict__ qkv, bf16* __restrict__ Vt) {
    int bh = blockIdx.x;
    int b = bh >> 3, h = bh & 7;
    __shared__ short tile[64][33];
    const short* q = (const short*)qkv;
    short* vt = (short*)Vt;
    for (int s0 = 0; s0 < 512; s0 += 64) {
        for (int t = threadIdx.x; t < 64 * 32; t += 256) {
            int s = t >> 5, d = t & 31;
            tile[s][d] = q[(long)((b << 9) + s0 + s) * 768 + 512 + h * 32 + d];
        }
        __syncthreads();
        for (int t = threadIdx.x; t < 64 * 32; t += 256) {
            int d = t >> 6, s = t & 63;
            vt[((long)(bh * 32) + d) * 512 + s0 + s] = tile[s][d];
        }
        __syncthreads();
    }
}

// ---------------- fused flash attention (MFMA) ------------------------------
// grid (4 q-tiles, B*H); 4 waves x 32 q-rows; qkv (M,768) bf16, Vt (B*H,32,512)
#define PSTR 136  // Ps row stride in shorts (128 + 8 pad, keeps 16B align)
__global__ __launch_bounds__(256) void fattn_kernel(const bf16* __restrict__ qkv,
                                                    const bf16* __restrict__ Vt,
                                                    const float* __restrict__ bias_l,
                                                    bf16* __restrict__ ctx) {
    __shared__ __align__(16) short Ks[128 * 32];      // K tile [j][32d]
    __shared__ __align__(16) short Vs[32 * 128];      // V^T tile [d][128j]
    __shared__ __align__(16) short Ps[4 * 32 * PSTR]; // per-wave P [32q][128j]
    __shared__ float bias_s[640];
    int tid = threadIdx.x;
    int wave = tid >> 6, lane = tid & 63;
    int frow = lane & 15, fquad = lane >> 4;
    int bh = blockIdx.y;
    int b = bh >> 3, h = bh & 7;
    int i0 = blockIdx.x * 128;
    int wm = wave * 32;
    const float scale = 0.17677669529663687f;  // 32^-0.5

    for (int t = tid; t < 639; t += 256) bias_s[t] = bias_l[(i0 + t) * 8 + h];

    // Q fragments (A-layout: m=frow, k=fquad*8..+8), held for whole block
    short8 qf[2];
#pragma unroll
    for (int i = 0; i < 2; ++i)
        qf[i] = *(const short8*)((const short*)qkv +
                 (long)((b << 9) + i0 + wm + i * 16 + frow) * 768 + h * 32 + fquad * 8);

    const char* gK = (const char*)qkv + (long)b * 512 * 1536 + 512 + h * 64;
    const char* gV = (const char*)Vt + (long)bh * 32 * 1024;

    floatx4 acc_o[2][2] = {};
    float run_m[2][4], run_l[2][4];
#pragma unroll
    for (int i = 0; i < 2; ++i)
#pragma unroll
        for (int r = 0; r < 4; ++r) { run_m[i][r] = -1e30f; run_l[i][r] = 0.0f; }

    short* Pw = Ps + wave * 32 * PSTR;
    bf16* Pb = (bf16*)Pw;

    for (int j0 = 0; j0 < 512; j0 += 128) {
        // stage K tile (128 rows x 64B) and Vt tile (32 rows x 256B)
        {
            char* lpK = (char*)Ks + (tid & 192) * 16;
            char* lpV = (char*)Vs + (tid & 192) * 16;
#pragma unroll
            for (int r = 0; r < 2; ++r) {
                int off = r * 4096 + tid * 16;
                const char* gp = gK + (long)(j0 + (off >> 6)) * 1536 + (off & 63);
                __builtin_amdgcn_global_load_lds((const __attribute__((address_space(1))) void*)gp,
                                                 (__attribute__((address_space(3))) void*)(lpK + r * 4096), 16, 0, 0);
            }
#pragma unroll
            for (int r = 0; r < 2; ++r) {
                int off = r * 4096 + tid * 16;
                const char* gp = gV + (long)(off >> 8) * 1024 + j0 * 2 + (off & 255);
                __builtin_amdgcn_global_load_lds((const __attribute__((address_space(1))) void*)gp,
                                                 (__attribute__((address_space(3))) void*)(lpV + r * 4096), 16, 0, 0);
            }
        }
        __syncthreads();

        // S = Q K^T  (wave: 32 q-rows x 128 keys)
        floatx4 accs[2][8] = {};
#pragma unroll
        for (int jt = 0; jt < 8; ++jt) {
            short8 bk = *(const short8*)(Ks + (jt * 16 + frow) * 32 + fquad * 8);
#pragma unroll
            for (int i = 0; i < 2; ++i)
                accs[i][jt] = __builtin_amdgcn_mfma_f32_16x16x32_bf16(qf[i], bk, accs[i][jt], 0, 0, 0);
        }
        // scale + relative bias
#pragma unroll
        for (int i = 0; i < 2; ++i) {
            int irel = wm + i * 16 + fquad * 4;
#pragma unroll
            for (int jt = 0; jt < 8; ++jt) {
                int jl = j0 + jt * 16 + frow;
#pragma unroll
                for (int r = 0; r < 4; ++r)
                    accs[i][jt][r] = accs[i][jt][r] * scale + bias_s[irel + r + 511 - jl];
            }
        }
        // online softmax (row state replicated across frow lanes)
#pragma unroll
        for (int i = 0; i < 2; ++i) {
#pragma unroll
            for (int r = 0; r < 4; ++r) {
                float m = -1e30f;
#pragma unroll
                for (int jt = 0; jt < 8; ++jt) m = fmaxf(m, accs[i][jt][r]);
                m = fmaxf(m, __shfl_xor(m, 1));
                m = fmaxf(m, __shfl_xor(m, 2));
                m = fmaxf(m, __shfl_xor(m, 4));
                m = fmaxf(m, __shfl_xor(m, 8));
                float nm = fmaxf(run_m[i][r], m);
                float al = __expf(run_m[i][r] - nm);
                run_m[i][r] = nm;
                float ts = 0.0f;
#pragma unroll
                for (int jt = 0; jt < 8; ++jt) {
                    float p = __expf(accs[i][jt][r] - nm);
                    accs[i][jt][r] = p;
                    ts += p;
                }
                ts += __shfl_xor(ts, 1);
                ts += __shfl_xor(ts, 2);
                ts += __shfl_xor(ts, 4);
                ts += __shfl_xor(ts, 8);
                run_l[i][r] = run_l[i][r] * al + ts;
                acc_o[i][0][r] *= al;
                acc_o[i][1][r] *= al;
            }
        }
        // P -> LDS (C/D layout -> row-major), then PV via MFMA
#pragma unroll
        for (int i = 0; i < 2; ++i)
#pragma unroll
            for (int jt = 0; jt < 8; ++jt)
#pragma unroll
                for (int r = 0; r < 4; ++r)
                    Pb[(i * 16 + fquad * 4 + r) * PSTR + jt * 16 + frow] = f2b(accs[i][jt][r]);
#pragma unroll
        for (int ks = 0; ks < 4; ++ks) {
            short8 ap[2], bv[2];
#pragma unroll
            for (int i = 0; i < 2; ++i)
                ap[i] = *(const short8*)(Pw + (i * 16 + frow) * PSTR + ks * 32 + fquad * 8);
#pragma unroll
            for (int dt = 0; dt < 2; ++dt)
                bv[dt] = *(const short8*)(Vs + (dt * 16 + frow) * 128 + ks * 32 + fquad * 8);
#pragma unroll
            for (int i = 0; i < 2; ++i)
#pragma unroll
                for (int dt = 0; dt < 2; ++dt)
                    acc_o[i][dt] = __builtin_amdgcn_mfma_f32_16x16x32_bf16(ap[i], bv[dt], acc_o[i][dt], 0, 0, 0);
        }
        __syncthreads();
    }

    // epilogue: O /= l, write ctx (M,256)
#pragma unroll
    for (int i = 0; i < 2; ++i) {
#pragma unroll
        for (int r = 0; r < 4; ++r) {
            float inv = 1.0f / run_l[i][r];
            int row = i0 + wm + i * 16 + fquad * 4 + r;
#pragma unroll
            for (int dt = 0; dt < 2; ++dt) {
                int d = dt * 16 + frow;
                ctx[(long)((b << 9) + row) * 256 + h * 32 + d] = f2b(acc_o[i][dt][r] * inv);
            }
        }
    }
}

extern "C" void kernel_launch(void* const* d_in, const int* in_sizes, int n_in,
                              void* d_out, int out_size, void* d_ws, size_t ws_size,
                              hipStream_t stream) {
    const float* x        = (const float*)d_in[0];
    const float* conv1_w  = (const float*)d_in[1];
    const float* conv1_b  = (const float*)d_in[2];
    const float* bn1_g    = (const float*)d_in[3];
    const float* bn1_b    = (const float*)d_in[4];
    const float* conv2_w  = (const float*)d_in[5];
    const float* conv2_b  = (const float*)d_in[6];
    const float* bn2_g    = (const float*)d_in[7];
    const float* bn2_b    = (const float*)d_in[8];
    const float* ln1_g    = (const float*)d_in[9];
    const float* ln1_b    = (const float*)d_in[10];
    const float* wq       = (const float*)d_in[11];
    const float* wk       = (const float*)d_in[12];
    const float* wv       = (const float*)d_in[13];
    const float* wo       = (const float*)d_in[14];
    const float* bo       = (const float*)d_in[15];
    const float* bias_tab = (const float*)d_in[16];
    const float* ln2_g    = (const float*)d_in[17];
    const float* ln2_b    = (const float*)d_in[18];
    const float* w1       = (const float*)d_in[19];
    const float* b1       = (const float*)d_in[20];
    const float* w2       = (const float*)d_in[21];
    const float* b2       = (const float*)d_in[22];
    const float* fn_g     = (const float*)d_in[23];
    const float* fn_b     = (const float*)d_in[24];
    (void)in_sizes; (void)n_in; (void)out_size; (void)ws_size;

    const int M = B_ * S_;  // 8192
    char* wsb = (char*)d_ws;
    float* t    = (float*)wsb;                          // [0, 8M)
    bf16* qkv   = (bf16*)(wsb + (8u << 20));            // [8M, 20M)
    bf16* h1    = (bf16*)(wsb + (8u << 20));            // alias (4 MB, dead before qkv)
    char* reg2  = wsb + (20u << 20);                    // [20M, 40M)
    bf16* ff1   = (bf16*)reg2;                          // 16 MB (FF1 -> FF2 only)
    bf16* Vt    = (bf16*)reg2;                          // alias: live QKV-GEMM -> attn only
    bf16* xnctx = (bf16*)(reg2 + (16u << 20));          // 4 MB (xn and ctx)
    bf16* col1  = (bf16*)reg2;                          // alias (tokenizer only)
    bf16* col2  = (bf16*)reg2;                          // alias (tokenizer only)
    bf16* wqkvT = (bf16*)(wsb + (40u << 20));           // L*768*256
    bf16* woT   = wqkvT + (long)L_ * 768 * 256;         // L*256*256
    bf16* w1T   = woT + (long)L_ * 256 * 256;           // L*1024*256
    bf16* w2T   = w1T + (long)L_ * 1024 * 256;          // L*256*1024
    bf16* c1w   = w2T + (long)L_ * 256 * 1024;          // 256*224
    bf16* c2w   = c1w + 256 * 224;                      // 256*1280
    float* sh1  = (float*)(c2w + 256 * 1280);           // 256
    float* sh2  = sh1 + 256;                            // 256

    // ---- weight prep ----
    wtrans_kernel<<<dim3(8, 8, L_), 256, 0, stream>>>(wq, wqkvT, 256, 256, 65536, 768 * 256, 0);
    wtrans_kernel<<<dim3(8, 8, L_), 256, 0, stream>>>(wk, wqkvT, 256, 256, 65536, 768 * 256, 256);
    wtrans_kernel<<<dim3(8, 8, L_), 256, 0, stream>>>(wv, wqkvT, 256, 256, 65536, 768 * 256, 512);
    wtrans_kernel<<<dim3(8, 8, L_), 256, 0, stream>>>(wo, woT, 256, 256, 65536, 65536, 0);
    wtrans_kernel<<<dim3(32, 8, L_), 256, 0, stream>>>(w1, w1T, 256, 1024, 262144, 262144, 0);
    wtrans_kernel<<<dim3(8, 32, L_), 256, 0, stream>>>(w2, w2T, 1024, 256, 262144, 262144, 0);
    convprep_kernel<<<32, 256, 0, stream>>>(conv1_w, conv1_b, bn1_g, bn1_b,
                                            conv2_w, conv2_b, bn2_g, bn2_b,
                                            c1w, c2w, sh1, sh2);

    // ---- tokenizer ----
    im2col1_kernel<<<dim3(7, B_), 256, 0, stream>>>(x, col1);
    gemm_bf16<128, 64, 32, 64, FB | FG | FO16><<<dim3(4, 64), 256, 0, stream>>>(
        col1, c1w, sh1, nullptr, nullptr, h1, M, 256, 224);
    im2col2_kernel<<<dim3(5, B_), 256, 0, stream>>>(h1, col2);
    gemm_bf16<128, 64, 32, 64, FB | FG | FPE><<<dim3(4, 64), 256, 0, stream>>>(
        col2, c2w, sh2, nullptr, t, nullptr, M, 256, 1280);

    // ---- transformer layers ----
    for (int l = 0; l < L_; ++l) {
        ln_kernel<true><<<M, 256, 0, stream>>>(t, ln1_g + l * D_, ln1_b + l * D_, nullptr, xnctx);
        gemm_bf16<128, 128, 64, 64, FO16><<<dim3(6, 64), 256, 0, stream>>>(
            xnctx, wqkvT + (long)l * 768 * 256, nullptr, nullptr, nullptr, qkv, M, 768, 256);
        vtrans_kernel<<<B_ * H_, 256, 0, stream>>>(qkv, Vt);
        fattn_kernel<<<dim3(4, B_ * H_), 256, 0, stream>>>(
            qkv, Vt, bias_tab + (long)l * (2 * S_ - 1) * H_, xnctx);
        gemm_bf16<128, 64, 32, 64, FB | FR><<<dim3(4, 64), 256, 0, stream>>>(
            xnctx, woT + (long)l * 65536, bo + l * D_, t, t, nullptr, M, 256, 256);
        ln_kernel<true><<<M, 256, 0, stream>>>(t, ln2_g + l * D_, ln2_b + l * D_, nullptr, xnctx);
        gemm_bf16<128, 128, 64, 64, FB | FG | FO16><<<dim3(8, 64), 256, 0, stream>>>(
            xnctx, w1T + (long)l * 262144, b1 + l * FF_, nullptr, nullptr, ff1, M, 1024, 256);
        gemm_bf16<128, 64, 32, 64, FB | FR><<<dim3(4, 64), 256, 0, stream>>>(
            ff1, w2T + (long)l * 262144, b2 + l * D_, t, t, nullptr, M, 256, 1024);
    }
    ln_kernel<false><<<M, 256, 0, stream>>>(t, fn_g, fn_b, (float*)d_out, nullptr);
}

// Round 5
// 699.917 us; speedup vs baseline: 7.0291x; 1.2452x over previous
//
#include <hip/hip_runtime.h>
#include <hip/hip_bf16.h>
#include <stdint.h>

#define B_   16
#define CIN_ 32
#define S_   512
#define D_   256
#define H_   8
#define L_   4
#define FF_  1024
#define HD_  32
#define EPS_ 1e-5f

typedef __hip_bfloat16 bf16;
typedef __attribute__((ext_vector_type(8))) short short8;
typedef __attribute__((ext_vector_type(4))) float floatx4;

__device__ __forceinline__ float b2f(bf16 v) { return __bfloat162float(v); }
__device__ __forceinline__ bf16 f2b(float v) { return __float2bfloat16(v); }
__device__ __forceinline__ float gelu_f(float v) {
    return 0.5f * v * (1.0f + erff(v * 0.70710678118654752f));
}
__device__ __forceinline__ float pe_val(int s, int d) {
    int m2 = d & ~1;
    float div = expf((float)m2 * (-9.210340371976184f / 256.0f));
    float ang = (float)s * div * 0.5f;  // scale = D/S = 0.5
    return (d & 1) ? cosf(ang) : sinf(ang);
}

// ---------------- weight transpose-cast: dst[n][k] = src[k][n] --------------
__global__ void wtrans_kernel(const float* __restrict__ src, bf16* __restrict__ dst,
                              int K, int N, long lss, long lds_, int rowoff) {
    __shared__ float tile[32][33];
    int l = blockIdx.z;
    int n0 = blockIdx.x * 32, k0 = blockIdx.y * 32;
    int tx = threadIdx.x & 31, ty0 = threadIdx.x >> 5;
#pragma unroll
    for (int r = 0; r < 4; ++r) {
        int ky = r * 8 + ty0;
        tile[ky][tx] = src[l * lss + (long)(k0 + ky) * N + n0 + tx];
    }
    __syncthreads();
#pragma unroll
    for (int r = 0; r < 4; ++r) {
        int ny = r * 8 + ty0;
        dst[l * lds_ + (long)(rowoff + n0 + ny) * K + k0 + tx] = f2b(tile[tx][ny]);
    }
}

// ---------------- conv weight prep (fold BN scale) + shift vectors ----------
// c1w padded to K=256 (zeros beyond 224)
__global__ void convprep_kernel(const float* __restrict__ w1c, const float* __restrict__ cb1,
                                const float* __restrict__ g1, const float* __restrict__ bb1,
                                const float* __restrict__ w2c, const float* __restrict__ cb2,
                                const float* __restrict__ g2, const float* __restrict__ bb2,
                                bf16* __restrict__ c1w, bf16* __restrict__ c2w,
                                float* __restrict__ sh1, float* __restrict__ sh2) {
    int bid = blockIdx.x;
    int ty = threadIdx.x >> 4, t16 = threadIdx.x & 15;
    float rinv = rsqrtf(1.0f + EPS_);
    if (bid < 16) {
        int o = bid * 16 + ty;
        float scale = g1[o] * rinv;
        if (t16 == 0) sh1[o] = cb1[o] * scale + bb1[o];
        for (int j = t16; j < 256; j += 16) {
            int kk = j >> 5, i = j & 31;
            float v = (kk < 7) ? w1c[o * 224 + i * 7 + kk] * scale : 0.0f;
            c1w[o * 256 + kk * 32 + i] = f2b(v);
        }
    } else {
        int o = (bid - 16) * 16 + ty;
        float scale = g2[o] * rinv;
        if (t16 == 0) sh2[o] = cb2[o] * scale + bb2[o];
        for (int j = t16; j < D_ * 5; j += 16) {
            int i = j / 5, kk = j % 5;
            c2w[o * 1280 + kk * 256 + i] = f2b(w2c[o * 1280 + i * 5 + kk] * scale);
        }
    }
}

// ---------------- im2col for conv1: x (B,CIN,S) f32 -> col (B*S, 256) bf16 --
__global__ void im2col1_kernel(const float* __restrict__ x, bf16* __restrict__ col) {
    int kk = blockIdx.x, b = blockIdx.y;  // kk 0..7, kk==7 -> zero pad
    for (int t = threadIdx.x; t < 512 * 32; t += 256) {
        int s = t & 511, i = t >> 9;
        int sp = s + kk - 3;
        float v = (kk < 7 && sp >= 0 && sp < 512) ? x[((b << 5) + i) * 512 + sp] : 0.0f;
        col[(long)((b << 9) + s) * 256 + kk * 32 + i] = f2b(v);
    }
}

// ---------------- im2col for conv2: h1 (B*S, 256) bf16 -> col (B*S, 1280) ---
__global__ void im2col2_kernel(const bf16* __restrict__ h1, bf16* __restrict__ col) {
    int kk = blockIdx.x, b = blockIdx.y;
    for (int t = threadIdx.x; t < 512 * 32; t += 256) {
        int c = t & 31, s = t >> 5;
        int sp = s + kk - 2;
        uint4 v = {0u, 0u, 0u, 0u};
        if (sp >= 0 && sp < 512)
            v = *(const uint4*)((const char*)h1 + ((long)((b << 9) + sp) * 256 + c * 8) * 2);
        *(uint4*)((char*)col + ((long)((b << 9) + s) * 1280 + kk * 256 + c * 8) * 2) = v;
    }
}

// ---------------- layernorm (D=256): t f32 -> bf16 or f32 -------------------
template <bool OUT_BF16>
__global__ void ln_kernel(const float* __restrict__ x, const float* __restrict__ g,
                          const float* __restrict__ bt, float* __restrict__ out_f,
                          bf16* __restrict__ out_b) {
    int row = blockIdx.x;
    int tid = threadIdx.x;  // 256 == D
    float v = x[(long)row * D_ + tid];
    float s1 = v, s2 = v * v;
    __shared__ float red[8];
#pragma unroll
    for (int off = 32; off; off >>= 1) {
        s1 += __shfl_xor(s1, off);
        s2 += __shfl_xor(s2, off);
    }
    int wave = tid >> 6;
    if ((tid & 63) == 0) { red[wave] = s1; red[4 + wave] = s2; }
    __syncthreads();
    if (tid == 0) {
        float a = red[0] + red[1] + red[2] + red[3];
        float q = red[4] + red[5] + red[6] + red[7];
        float mu = a * (1.0f / D_);
        float var = q * (1.0f / D_) - mu * mu;
        red[0] = mu;
        red[1] = rsqrtf(var + EPS_);
    }
    __syncthreads();
    float y = (v - red[0]) * red[1] * g[tid] + bt[tid];
    if (OUT_BF16) out_b[(long)row * D_ + tid] = f2b(y);
    else          out_f[(long)row * D_ + tid] = y;
}

// ------- swizzled async staging: ROWS x 128B tile, 16B chunk XOR swizzle ----
// LDS slot s holds global chunk (row = s>>3, q = (s&7) ^ (row&7)).
template <int ROWS>
__device__ __forceinline__ void stage_sw(const char* gbase, long rs_bytes, int k_byte_off,
                                         char* lds_base, int tid) {
    constexpr int ROUNDS = ROWS / 32;
    char* lp = lds_base + (tid & 192) * 16;  // wave-uniform base
#pragma unroll
    for (int r = 0; r < ROUNDS; ++r) {
        int s = r * 256 + tid;
        int row = s >> 3;
        int q = ((s & 7) ^ (row & 7)) * 16;
        const char* gp = gbase + (long)row * rs_bytes + k_byte_off + q;
        __builtin_amdgcn_global_load_lds((const __attribute__((address_space(1))) void*)gp,
                                         (__attribute__((address_space(3))) void*)(lp + r * 4096),
                                         16, 0, 0);
    }
}
// fragment byte address inside swizzled tile: row m, chunk qc (0..7)
__device__ __forceinline__ int sw_off(int m, int qc) {
    return m * 128 + ((qc ^ (m & 7)) * 16);
}

// ------- bf16 MFMA GEMM, 64x64 tile, BK=64, double-buffered -----------------
enum { FB = 1, FG = 2, FR = 4, FO16 = 8, FPE = 16 };

template <int FLAGS>
__global__ __launch_bounds__(256) void gemm2(const bf16* __restrict__ A, const bf16* __restrict__ Wt,
                                             const float* __restrict__ bias, const float* __restrict__ res,
                                             float* __restrict__ outf, bf16* __restrict__ outb,
                                             int M, int N, int K) {
    __shared__ __align__(16) short As[2][64 * 64];
    __shared__ __align__(16) short Bs[2][64 * 64];
    int tid = threadIdx.x;
    int wave = tid >> 6, lane = tid & 63;
    int frow = lane & 15, fquad = lane >> 4;
    int m0 = blockIdx.y * 64, n0 = blockIdx.x * 64;
    int wm = (wave & 1) * 32, wn = (wave >> 1) * 32;
    floatx4 acc[2][2] = {};
    const char* Ab = (const char*)A + (long)m0 * K * 2;
    const char* Bb = (const char*)Wt + (long)n0 * K * 2;
    long rs = (long)K * 2;
    int KT = K >> 6;
    stage_sw<64>(Ab, rs, 0, (char*)As[0], tid);
    stage_sw<64>(Bb, rs, 0, (char*)Bs[0], tid);
    for (int kt = 0; kt < KT; ++kt) {
        int cur = kt & 1;
        __syncthreads();  // drains staging of buf[cur]; protects buf[1-cur] reuse
        if (kt + 1 < KT) {
            stage_sw<64>(Ab, rs, (kt + 1) * 128, (char*)As[1 - cur], tid);
            stage_sw<64>(Bb, rs, (kt + 1) * 128, (char*)Bs[1 - cur], tid);
        }
        const char* Ap = (const char*)As[cur];
        const char* Bp = (const char*)Bs[cur];
#pragma unroll
        for (int kh = 0; kh < 2; ++kh) {
            short8 af[2], bw[2];
#pragma unroll
            for (int i = 0; i < 2; ++i) {
                int m = wm + i * 16 + frow;
                af[i] = *(const short8*)(Ap + sw_off(m, kh * 4 + fquad));
            }
#pragma unroll
            for (int j = 0; j < 2; ++j) {
                int n = wn + j * 16 + frow;
                bw[j] = *(const short8*)(Bp + sw_off(n, kh * 4 + fquad));
            }
#pragma unroll
            for (int i = 0; i < 2; ++i)
#pragma unroll
                for (int j = 0; j < 2; ++j)
                    acc[i][j] = __builtin_amdgcn_mfma_f32_16x16x32_bf16(af[i], bw[j], acc[i][j], 0, 0, 0);
        }
    }
#pragma unroll
    for (int i = 0; i < 2; ++i) {
#pragma unroll
        for (int j = 0; j < 2; ++j) {
#pragma unroll
            for (int r = 0; r < 4; ++r) {
                int row = m0 + wm + i * 16 + fquad * 4 + r;
                int col = n0 + wn + j * 16 + frow;
                float v = acc[i][j][r];
                if (FLAGS & FB) v += bias[col];
                if (FLAGS & FG) v = gelu_f(v);
                if (FLAGS & FPE) v += pe_val(row & 511, col);
                if (FLAGS & FR) v += res[(long)row * N + col];
                if (FLAGS & FO16) outb[(long)row * N + col] = f2b(v);
                else              outf[(long)row * N + col] = v;
            }
        }
    }
}

// ---------------- V transpose: qkv (M,768) cols 512..767 -> Vt (B*H,32,512) -
__global__ void vtrans_kernel(const bf16* __restrict__ qkv, bf16* __restrict__ Vt) {
    int bh = blockIdx.x;
    int b = bh >> 3, h = bh & 7;
    __shared__ short tile[64][33];
    const short* q = (const short*)qkv;
    short* vt = (short*)Vt;
    for (int s0 = 0; s0 < 512; s0 += 64) {
        for (int t = threadIdx.x; t < 64 * 32; t += 256) {
            int s = t >> 5, d = t & 31;
            tile[s][d] = q[(long)((b << 9) + s0 + s) * 768 + 512 + h * 32 + d];
        }
        __syncthreads();
        for (int t = threadIdx.x; t < 64 * 32; t += 256) {
            int d = t >> 6, s = t & 63;
            vt[((long)(bh * 32) + d) * 512 + s0 + s] = tile[s][d];
        }
        __syncthreads();
    }
}

// ---------------- fused flash attention (MFMA) ------------------------------
#define PSTR 136
__global__ __launch_bounds__(256) void fattn_kernel(const bf16* __restrict__ qkv,
                                                    const bf16* __restrict__ Vt,
                                                    const float* __restrict__ bias_l,
                                                    bf16* __restrict__ ctx) {
    __shared__ __align__(16) short Ks[128 * 32];
    __shared__ __align__(16) short Vs[32 * 128];
    __shared__ __align__(16) short Ps[4 * 32 * PSTR];
    __shared__ float bias_s[640];
    int tid = threadIdx.x;
    int wave = tid >> 6, lane = tid & 63;
    int frow = lane & 15, fquad = lane >> 4;
    int bh = blockIdx.y;
    int b = bh >> 3, h = bh & 7;
    int i0 = blockIdx.x * 128;
    int wm = wave * 32;
    const float scale = 0.17677669529663687f;

    for (int t = tid; t < 639; t += 256) bias_s[t] = bias_l[(i0 + t) * 8 + h];

    short8 qf[2];
#pragma unroll
    for (int i = 0; i < 2; ++i)
        qf[i] = *(const short8*)((const short*)qkv +
                 (long)((b << 9) + i0 + wm + i * 16 + frow) * 768 + h * 32 + fquad * 8);

    const char* gK = (const char*)qkv + (long)b * 512 * 1536 + 512 + h * 64;
    const char* gV = (const char*)Vt + (long)bh * 32 * 1024;

    floatx4 acc_o[2][2] = {};
    float run_m[2][4], run_l[2][4];
#pragma unroll
    for (int i = 0; i < 2; ++i)
#pragma unroll
        for (int r = 0; r < 4; ++r) { run_m[i][r] = -1e30f; run_l[i][r] = 0.0f; }

    short* Pw = Ps + wave * 32 * PSTR;
    bf16* Pb = (bf16*)Pw;

    for (int j0 = 0; j0 < 512; j0 += 128) {
        {
            char* lpK = (char*)Ks + (tid & 192) * 16;
            char* lpV = (char*)Vs + (tid & 192) * 16;
#pragma unroll
            for (int r = 0; r < 2; ++r) {
                int off = r * 4096 + tid * 16;
                const char* gp = gK + (long)(j0 + (off >> 6)) * 1536 + (off & 63);
                __builtin_amdgcn_global_load_lds((const __attribute__((address_space(1))) void*)gp,
                                                 (__attribute__((address_space(3))) void*)(lpK + r * 4096), 16, 0, 0);
            }
#pragma unroll
            for (int r = 0; r < 2; ++r) {
                int off = r * 4096 + tid * 16;
                const char* gp = gV + (long)(off >> 8) * 1024 + j0 * 2 + (off & 255);
                __builtin_amdgcn_global_load_lds((const __attribute__((address_space(1))) void*)gp,
                                                 (__attribute__((address_space(3))) void*)(lpV + r * 4096), 16, 0, 0);
            }
        }
        __syncthreads();

        floatx4 accs[2][8] = {};
#pragma unroll
        for (int jt = 0; jt < 8; ++jt) {
            short8 bk = *(const short8*)(Ks + (jt * 16 + frow) * 32 + fquad * 8);
#pragma unroll
            for (int i = 0; i < 2; ++i)
                accs[i][jt] = __builtin_amdgcn_mfma_f32_16x16x32_bf16(qf[i], bk, accs[i][jt], 0, 0, 0);
        }
#pragma unroll
        for (int i = 0; i < 2; ++i) {
            int irel = wm + i * 16 + fquad * 4;
#pragma unroll
            for (int jt = 0; jt < 8; ++jt) {
                int jl = j0 + jt * 16 + frow;
#pragma unroll
                for (int r = 0; r < 4; ++r)
                    accs[i][jt][r] = accs[i][jt][r] * scale + bias_s[irel + r + 511 - jl];
            }
        }
#pragma unroll
        for (int i = 0; i < 2; ++i) {
#pragma unroll
            for (int r = 0; r < 4; ++r) {
                float m = -1e30f;
#pragma unroll
                for (int jt = 0; jt < 8; ++jt) m = fmaxf(m, accs[i][jt][r]);
                m = fmaxf(m, __shfl_xor(m, 1));
                m = fmaxf(m, __shfl_xor(m, 2));
                m = fmaxf(m, __shfl_xor(m, 4));
                m = fmaxf(m, __shfl_xor(m, 8));
                float nm = fmaxf(run_m[i][r], m);
                float al = __expf(run_m[i][r] - nm);
                run_m[i][r] = nm;
                float ts = 0.0f;
#pragma unroll
                for (int jt = 0; jt < 8; ++jt) {
                    float p = __expf(accs[i][jt][r] - nm);
                    accs[i][jt][r] = p;
                    ts += p;
                }
                ts += __shfl_xor(ts, 1);
                ts += __shfl_xor(ts, 2);
                ts += __shfl_xor(ts, 4);
                ts += __shfl_xor(ts, 8);
                run_l[i][r] = run_l[i][r] * al + ts;
                acc_o[i][0][r] *= al;
                acc_o[i][1][r] *= al;
            }
        }
#pragma unroll
        for (int i = 0; i < 2; ++i)
#pragma unroll
            for (int jt = 0; jt < 8; ++jt)
#pragma unroll
                for (int r = 0; r < 4; ++r)
                    Pb[(i * 16 + fquad * 4 + r) * PSTR + jt * 16 + frow] = f2b(accs[i][jt][r]);
#pragma unroll
        for (int ks = 0; ks < 4; ++ks) {
            short8 ap[2], bv[2];
#pragma unroll
            for (int i = 0; i < 2; ++i)
                ap[i] = *(const short8*)(Pw + (i * 16 + frow) * PSTR + ks * 32 + fquad * 8);
#pragma unroll
            for (int dt = 0; dt < 2; ++dt)
                bv[dt] = *(const short8*)(Vs + (dt * 16 + frow) * 128 + ks * 32 + fquad * 8);
#pragma unroll
            for (int i = 0; i < 2; ++i)
#pragma unroll
                for (int dt = 0; dt < 2; ++dt)
                    acc_o[i][dt] = __builtin_amdgcn_mfma_f32_16x16x32_bf16(ap[i], bv[dt], acc_o[i][dt], 0, 0, 0);
        }
        __syncthreads();
    }

#pragma unroll
    for (int i = 0; i < 2; ++i) {
#pragma unroll
        for (int r = 0; r < 4; ++r) {
            float inv = 1.0f / run_l[i][r];
            int row = i0 + wm + i * 16 + fquad * 4 + r;
#pragma unroll
            for (int dt = 0; dt < 2; ++dt) {
                int d = dt * 16 + frow;
                ctx[(long)((b << 9) + row) * 256 + h * 32 + d] = f2b(acc_o[i][dt][r] * inv);
            }
        }
    }
}

extern "C" void kernel_launch(void* const* d_in, const int* in_sizes, int n_in,
                              void* d_out, int out_size, void* d_ws, size_t ws_size,
                              hipStream_t stream) {
    const float* x        = (const float*)d_in[0];
    const float* conv1_w  = (const float*)d_in[1];
    const float* conv1_b  = (const float*)d_in[2];
    const float* bn1_g    = (const float*)d_in[3];
    const float* bn1_b    = (const float*)d_in[4];
    const float* conv2_w  = (const float*)d_in[5];
    const float* conv2_b  = (const float*)d_in[6];
    const float* bn2_g    = (const float*)d_in[7];
    const float* bn2_b    = (const float*)d_in[8];
    const float* ln1_g    = (const float*)d_in[9];
    const float* ln1_b    = (const float*)d_in[10];
    const float* wq       = (const float*)d_in[11];
    const float* wk       = (const float*)d_in[12];
    const float* wv       = (const float*)d_in[13];
    const float* wo       = (const float*)d_in[14];
    const float* bo       = (const float*)d_in[15];
    const float* bias_tab = (const float*)d_in[16];
    const float* ln2_g    = (const float*)d_in[17];
    const float* ln2_b    = (const float*)d_in[18];
    const float* w1       = (const float*)d_in[19];
    const float* b1       = (const float*)d_in[20];
    const float* w2       = (const float*)d_in[21];
    const float* b2       = (const float*)d_in[22];
    const float* fn_g     = (const float*)d_in[23];
    const float* fn_b     = (const float*)d_in[24];
    (void)in_sizes; (void)n_in; (void)out_size; (void)ws_size;

    const int M = B_ * S_;  // 8192
    char* wsb = (char*)d_ws;
    float* t    = (float*)wsb;                          // [0, 8M)
    bf16* qkv   = (bf16*)(wsb + (8u << 20));            // [8M, 20M)
    bf16* h1    = (bf16*)(wsb + (8u << 20));            // alias (4 MB, dead before qkv)
    char* reg2  = wsb + (20u << 20);                    // [20M, 40M)
    bf16* ff1   = (bf16*)reg2;                          // 16 MB (FF1 -> FF2 only)
    bf16* Vt    = (bf16*)reg2;                          // alias: QKV-GEMM -> attn only
    bf16* xnctx = (bf16*)(reg2 + (16u << 20));          // 4 MB (xn and ctx)
    bf16* col1  = (bf16*)reg2;                          // alias (tokenizer only, 4 MB)
    bf16* col2  = (bf16*)reg2;                          // alias (tokenizer only, 20 MB)
    bf16* wqkvT = (bf16*)(wsb + (40u << 20));           // L*768*256
    bf16* woT   = wqkvT + (long)L_ * 768 * 256;         // L*256*256
    bf16* w1T   = woT + (long)L_ * 256 * 256;           // L*1024*256
    bf16* w2T   = w1T + (long)L_ * 1024 * 256;          // L*256*1024
    bf16* c1w   = w2T + (long)L_ * 256 * 1024;          // 256*256 (padded K)
    bf16* c2w   = c1w + 256 * 256;                      // 256*1280
    float* sh1  = (float*)(c2w + 256 * 1280);           // 256
    float* sh2  = sh1 + 256;                            // 256

    // ---- weight prep ----
    wtrans_kernel<<<dim3(8, 8, L_), 256, 0, stream>>>(wq, wqkvT, 256, 256, 65536, 768 * 256, 0);
    wtrans_kernel<<<dim3(8, 8, L_), 256, 0, stream>>>(wk, wqkvT, 256, 256, 65536, 768 * 256, 256);
    wtrans_kernel<<<dim3(8, 8, L_), 256, 0, stream>>>(wv, wqkvT, 256, 256, 65536, 768 * 256, 512);
    wtrans_kernel<<<dim3(8, 8, L_), 256, 0, stream>>>(wo, woT, 256, 256, 65536, 65536, 0);
    wtrans_kernel<<<dim3(32, 8, L_), 256, 0, stream>>>(w1, w1T, 256, 1024, 262144, 262144, 0);
    wtrans_kernel<<<dim3(8, 32, L_), 256, 0, stream>>>(w2, w2T, 1024, 256, 262144, 262144, 0);
    convprep_kernel<<<32, 256, 0, stream>>>(conv1_w, conv1_b, bn1_g, bn1_b,
                                            conv2_w, conv2_b, bn2_g, bn2_b,
                                            c1w, c2w, sh1, sh2);

    // ---- tokenizer ----
    im2col1_kernel<<<dim3(8, B_), 256, 0, stream>>>(x, col1);
    gemm2<FB | FG | FO16><<<dim3(4, 128), 256, 0, stream>>>(
        col1, c1w, sh1, nullptr, nullptr, h1, M, 256, 256);
    im2col2_kernel<<<dim3(5, B_), 256, 0, stream>>>(h1, col2);
    gemm2<FB | FG | FPE><<<dim3(4, 128), 256, 0, stream>>>(
        col2, c2w, sh2, nullptr, t, nullptr, M, 256, 1280);

    // ---- transformer layers ----
    for (int l = 0; l < L_; ++l) {
        ln_kernel<true><<<M, 256, 0, stream>>>(t, ln1_g + l * D_, ln1_b + l * D_, nullptr, xnctx);
        gemm2<FO16><<<dim3(12, 128), 256, 0, stream>>>(
            xnctx, wqkvT + (long)l * 768 * 256, nullptr, nullptr, nullptr, qkv, M, 768, 256);
        vtrans_kernel<<<B_ * H_, 256, 0, stream>>>(qkv, Vt);
        fattn_kernel<<<dim3(4, B_ * H_), 256, 0, stream>>>(
            qkv, Vt, bias_tab + (long)l * (2 * S_ - 1) * H_, xnctx);
        gemm2<FB | FR><<<dim3(4, 128), 256, 0, stream>>>(
            xnctx, woT + (long)l * 65536, bo + l * D_, t, t, nullptr, M, 256, 256);
        ln_kernel<true><<<M, 256, 0, stream>>>(t, ln2_g + l * D_, ln2_b + l * D_, nullptr, xnctx);
        gemm2<FB | FG | FO16><<<dim3(16, 128), 256, 0, stream>>>(
            xnctx, w1T + (long)l * 262144, b1 + l * FF_, nullptr, nullptr, ff1, M, 1024, 256);
        gemm2<FB | FR><<<dim3(4, 128), 256, 0, stream>>>(
            ff1, w2T + (long)l * 262144, b2 + l * D_, t, t, nullptr, M, 256, 1024);
    }
    ln_kernel<false><<<M, 256, 0, stream>>>(t, fn_g, fn_b, (float*)d_out, nullptr);
}